// Round 10
// baseline (198.494 us; speedup 1.0000x reference)
//
#include <hip/hip_runtime.h>
#include <hip/hip_bf16.h>
#include <stdint.h>

// Problem constants
#define B_  64
#define C_  3
#define H_  512
#define W_  512
#define OC_ 16
#define OH_ 510
#define OW_ 510

// Tile geometry: 256-thread block -> 64(x) x 16(y) outputs; wave wv owns rows
// 4wv..4wv+3; per wave 16 MFMA sets (4 rows x 4 sx), 2 MFMAs per set (K=36).
#define TX_ 64
#define TY_ 16
#define TILES_X_ 8    // ceil(510/64)
#define TILES_Y_ 32   // ceil(510/16)
#define SMH_ 18       // value rows per channel (TY+2)
#define PXW_ 68       // u32 pair slots per row (x=0..67; reads reach x=65)

typedef __attribute__((ext_vector_type(8))) short bf16x8;   // MFMA A/B frag
typedef __attribute__((ext_vector_type(4))) float f32x4;    // MFMA C/D frag

// NaN-safe tanh: 1 - 2/(e^{2x}+1); e=inf -> 1 (no inf/inf NaN).
__device__ __forceinline__ float fast_tanh(float v) {
    float e = __expf(2.0f * v);
    return 1.0f - 2.0f * __builtin_amdgcn_rcpf(e + 1.0f);
}
__device__ __forceinline__ uint16_t bf16u(float f) {
    __hip_bfloat16 h = __float2bfloat16(f);   // RNE
    return __builtin_bit_cast(uint16_t, h);
}
__device__ __forceinline__ uint32_t pack2bf(float v0, float v1) {
    return (uint32_t)bf16u(v0) | ((uint32_t)bf16u(v1) << 16);
}
__device__ __forceinline__ float selg(const float v[4], int s) {
    float r = v[0];
    r = (s == 1) ? v[1] : r;
    r = (s == 2) ? v[2] : r;
    r = (s == 3) ? v[3] : r;
    return r;
}

// Row ids R = c*3+ky (0..8). Bank-balanced slot assignment (bank base mod 32
// of row R is 4*(c*18+ky) mod 32):
//   slot0 rows per g: {0(c0ky0):0, 5(c1ky2):16, 1(c0ky1):4, 7(c2ky1):20}  -> 2 lanes/bank, FREE
//   slot1 rows per g: {2(c0ky2):8, 3(c1ky0):8, 4(c1ky1):12, 6(c2ky0):16}  -> ~2.75-way
// B reg j: j0=slot0+xs0, j1=slot0+xs2, j2=slot1+xs0, j3=slot1+xs2; k=8g+2j+h, kx=xs+h.
// MFMA2: R=8 (c2ky2), xs0/xs2 at g==0 slots; B-side broadcast (free).

// ---- prep kernel: bake permuted A-fragments + bias into ws (3 KB) ----
// ws layout: [0) wf1 u16[64][8]; [1024) wf2 u16[64][8]; [2048) bias f32[64][4]
__global__ void conv_prep(const float* __restrict__ wgt,
                          const float* __restrict__ bias,
                          uint16_t* __restrict__ ws16) {
    const int lane = threadIdx.x;        // 0..63
    const int oc = lane & 15, g = lane >> 4;
    const int R0 = (g == 1) ? 5 : (g == 2) ? 1 : (g == 3) ? 7 : 0;
    const int R1 = (g == 1) ? 3 : (g == 2) ? 4 : (g == 3) ? 6 : 2;
    #pragma unroll
    for (int e = 0; e < 8; ++e) {
        int j = e >> 1, h = e & 1;
        int R  = (j < 2) ? R0 : R1;
        int kx = ((j & 1) << 1) + h;          // xs + h
        float w = (kx < 3) ? wgt[oc * 27 + 3 * R + kx] : 0.0f;
        ws16[lane * 8 + e] = bf16u(w);
        float w2 = 0.0f;
        if (g == 0 && e < 4 && kx < 3) w2 = wgt[oc * 27 + 24 + kx];  // R=8
        ws16[512 + lane * 8 + e] = bf16u(w2);
    }
    float* bv = (float*)(ws16 + 1024);
    #pragma unroll
    for (int r = 0; r < 4; ++r) bv[lane * 4 + r] = bias[g * 4 + r];
}

__global__ __launch_bounds__(256)
void conv3x3_min_tanh_mfma(const float* __restrict__ x,
                           const uint4* __restrict__ wsv,
                           float* __restrict__ out) {
    __shared__ uint32_t px[C_ * SMH_ * PXW_];   // 3672 u32 = 14688 B

    const int blk = blockIdx.x;
    const int bx = blk % TILES_X_;
    const int by = (blk / TILES_X_) % TILES_Y_;
    const int b  = blk / (TILES_X_ * TILES_Y_);
    const int ox0 = bx * TX_;
    const int oy0 = by * TY_;

    const int tid  = threadIdx.x;
    const int lane = tid & 63;
    const int wv   = tid >> 6;
    const int nf   = lane & 15;
    const int g    = lane >> 4;

    const float* xb = x + (size_t)b * (C_ * H_ * W_);

    // ---- staging: 32 lanes/row, float2 + 1 scalar -> 2 pairs, ds_write_b64 ----
    {
        const int l5    = tid & 31;         // 0..31 -> pairs 2*l5, 2*l5+1
        const int rbase = tid >> 5;         // 0..7
        const int x0    = 2 * l5;
        #pragma unroll
        for (int pass = 0; pass < 7; ++pass) {
            int rg = pass * 8 + rbase;      // 0..55
            if (rg < C_ * SMH_) {
                int c  = rg / SMH_;
                int rr = rg - SMH_ * c;
                int gy = min(oy0 + rr, H_ - 1);
                const float* xrow = xb + (c * H_ + gy) * W_;
                float2 v01 = *(const float2*)(xrow + ox0 + x0);     // in-bounds, 8B-aligned
                float  v2  = xrow[min(ox0 + x0 + 2, W_ - 1)];
                uint2 pk = make_uint2(pack2bf(v01.x, v01.y), pack2bf(v01.y, v2));
                *reinterpret_cast<uint2*>(&px[(c * SMH_ + rr) * PXW_ + x0]) = pk;
            }
        }
        // extras: pairs x=64,65 per (c,r): 108 single-shot items
        if (tid < C_ * SMH_ * 2) {
            int c   = (tid >= 36) + (tid >= 72);
            int rem = tid - 36 * c;
            int r   = rem >> 1;
            int xx  = 64 + (rem & 1);
            int gy  = min(oy0 + r, H_ - 1);
            const float* xrow = xb + (c * H_ + gy) * W_;
            float v0 = xrow[min(ox0 + xx,     W_ - 1)];
            float v1 = xrow[min(ox0 + xx + 1, W_ - 1)];
            px[(c * SMH_ + r) * PXW_ + xx] = pack2bf(v0, v1);
        }
    }

    // ---- baked fragments (coalesced dwordx4; L2/L3-hot, 3 KB total) ----
    bf16x8 wf1 = __builtin_bit_cast(bf16x8, wsv[lane]);
    bf16x8 wf2 = __builtin_bit_cast(bf16x8, wsv[64 + lane]);
    f32x4  bi  = __builtin_bit_cast(f32x4,  wsv[128 + lane]);

    // ---- loop-invariant slot bases (u32 elements); RL = c*18+ky of slot row
    const int rl0 = (g == 1) ? 20 : (g == 2) ? 1  : (g == 3) ? 37 : 0;   // rows {0,5,1,7}
    const int rl1 = (g == 1) ? 18 : (g == 2) ? 19 : (g == 3) ? 36 : 2;   // rows {2,3,4,6}
    const int base0 = (rl0 + 4 * wv) * PXW_ + nf;
    const int base1 = (rl1 + 4 * wv) * PXW_ + nf;
    const int base2 = (38  + 4 * wv) * PXW_ + nf;   // R=8: c2ky2 (broadcast)
    const int baddr = (lane ^ 32) << 2;             // hoisted ds_bpermute address

    __syncthreads();

    // ---- phase A: 16 sets, MFMAs + in-lane min only (no cross-lane) ----
    float mrow[4][4];
    #pragma unroll
    for (int row = 0; row < 4; ++row) {
        #pragma unroll
        for (int sx = 0; sx < 4; ++sx) {
            const int off = row * PXW_ + sx * 16;   // 0..252: ds_read2 imm range
            uint32_t r0 = px[base0 + off];
            uint32_t r1 = px[base0 + off + 2];
            uint32_t r2 = px[base1 + off];
            uint32_t r3 = px[base1 + off + 2];
            bf16x8 tf1 = __builtin_bit_cast(bf16x8, uint4{r0, r1, r2, r3});
            uint32_t s0 = px[base2 + off];
            uint32_t s1 = px[base2 + off + 2];
            bf16x8 tf2 = __builtin_bit_cast(bf16x8, uint4{s0, s1, 0u, 0u});

            f32x4 acc = __builtin_amdgcn_mfma_f32_16x16x32_bf16(wf1, tf1, bi, 0, 0, 0);
            acc = __builtin_amdgcn_mfma_f32_16x16x32_bf16(wf2, tf2, acc, 0, 0, 0);

            mrow[row][sx] = fminf(fminf(acc[0], acc[1]), fminf(acc[2], acc[3]));
        }
    }

    // ---- phase B: batched xor16 (16 independent swizzles), then per-row
    //      select-before-bpermute: only 4 xor32 ops total ----
    #pragma unroll
    for (int row = 0; row < 4; ++row)
        #pragma unroll
        for (int sx = 0; sx < 4; ++sx) {
            int sw = __builtin_amdgcn_ds_swizzle(
                __builtin_bit_cast(int, mrow[row][sx]), 0x401F);   // xor 16
            mrow[row][sx] = fminf(mrow[row][sx], __builtin_bit_cast(float, sw));
        }

    const size_t orow0 = ((size_t)b * OH_ + (oy0 + 4 * wv)) * OW_ + ox0;
    const int gx2 = g ^ 2;
    #pragma unroll
    for (int row = 0; row < 4; ++row) {
        float a = selg(mrow[row], g);     // own sx slice
        float c = selg(mrow[row], gx2);   // partner's needed slice
        int bp = __builtin_amdgcn_ds_bpermute(baddr, __builtin_bit_cast(int, c));
        float mm = fminf(a, __builtin_bit_cast(float, bp));
        float t = fast_tanh(fast_tanh(mm));

        int oy = oy0 + 4 * wv + row;
        int ox = ox0 + lane;
        if (oy < OH_ && ox < OW_)
            out[orow0 + (size_t)row * OW_ + lane] = t;
    }
}

extern "C" void kernel_launch(void* const* d_in, const int* in_sizes, int n_in,
                              void* d_out, int out_size, void* d_ws, size_t ws_size,
                              hipStream_t stream) {
    const float* x    = (const float*)d_in[0];
    const float* wgt  = (const float*)d_in[1];
    const float* bias = (const float*)d_in[2];
    float* out = (float*)d_out;

    conv_prep<<<1, 64, 0, stream>>>(wgt, bias, (uint16_t*)d_ws);
    conv3x3_min_tanh_mfma<<<dim3(B_ * TILES_X_ * TILES_Y_), 256, 0, stream>>>(
        x, (const uint4*)d_ws, out);
}

// Round 11
// 83.621 us; speedup vs baseline: 2.3737x; 2.3737x over previous
//
#include <hip/hip_runtime.h>
#include <hip/hip_bf16.h>
#include <stdint.h>

// Problem constants
#define B_  64
#define C_  3
#define H_  512
#define W_  512
#define OC_ 16
#define OH_ 510
#define OW_ 510

// Tile geometry: 256-thread block -> 64(x) x 16(y) outputs; wave wv owns rows
// 4wv..4wv+3; per wave 16 MFMA sets (4 rows x 4 sx), 2 MFMAs per set (K=36).
#define TX_ 64
#define TY_ 16
#define TILES_X_ 8    // ceil(510/64)
#define TILES_Y_ 32   // ceil(510/16)
#define SMH_ 18       // value rows per channel (TY+2)
#define PXW_ 68       // u32 pair slots per row (x=0..67; reads reach x=65)

typedef __attribute__((ext_vector_type(8))) short bf16x8;   // MFMA A/B frag
typedef __attribute__((ext_vector_type(4))) float f32x4;    // MFMA C/D frag

// NaN-safe tanh: 1 - 2/(e^{2x}+1); e=inf -> 1 (no inf/inf NaN).
__device__ __forceinline__ float fast_tanh(float v) {
    float e = __expf(2.0f * v);
    return 1.0f - 2.0f * __builtin_amdgcn_rcpf(e + 1.0f);
}
__device__ __forceinline__ uint16_t bf16u(float f) {
    __hip_bfloat16 h = __float2bfloat16(f);   // RNE
    return __builtin_bit_cast(uint16_t, h);
}
__device__ __forceinline__ uint32_t pack2bf(float v0, float v1) {
    return (uint32_t)bf16u(v0) | ((uint32_t)bf16u(v1) << 16);
}

// Row ids R = c*3+ky (0..8). Bank-balanced slot assignment (bank base mod 32
// of row R is 4*(c*18+ky) mod 32):
//   slot0 rows per g: {0:bank0, 5:16, 1:4, 7:20} -> 2 lanes/bank (free)
//   slot1 rows per g: {2:8, 3:8, 4:12, 6:16}     -> ~2.75-way
// B reg j: j0=slot0+xs0, j1=slot0+xs2, j2=slot1+xs0, j3=slot1+xs2; k=8g+2j+h.
// MFMA2: R=8 (c2ky2) at g==0 slots; B-side wave-broadcast (free).

// ---- prep kernel: bake permuted A-fragments + bias into ws (3 KB) ----
// ws layout: [0) wf1 u16[64][8]; [1024) wf2 u16[64][8]; [2048) bias f32[64][4]
__global__ void conv_prep(const float* __restrict__ wgt,
                          const float* __restrict__ bias,
                          uint16_t* __restrict__ ws16) {
    const int lane = threadIdx.x;        // 0..63
    const int oc = lane & 15, g = lane >> 4;
    const int R0 = (g == 1) ? 5 : (g == 2) ? 1 : (g == 3) ? 7 : 0;
    const int R1 = (g == 1) ? 3 : (g == 2) ? 4 : (g == 3) ? 6 : 2;
    #pragma unroll
    for (int e = 0; e < 8; ++e) {
        int j = e >> 1, h = e & 1;
        int R  = (j < 2) ? R0 : R1;
        int kx = ((j & 1) << 1) + h;          // xs + h
        float w = (kx < 3) ? wgt[oc * 27 + 3 * R + kx] : 0.0f;
        ws16[lane * 8 + e] = bf16u(w);
        float w2 = 0.0f;
        if (g == 0 && e < 4 && kx < 3) w2 = wgt[oc * 27 + 24 + kx];  // R=8
        ws16[512 + lane * 8 + e] = bf16u(w2);
    }
    float* bv = (float*)(ws16 + 1024);
    #pragma unroll
    for (int r = 0; r < 4; ++r) bv[lane * 4 + r] = bias[g * 4 + r];
}

__global__ __launch_bounds__(256)
void conv3x3_min_tanh_mfma(const float* __restrict__ x,
                           const uint4* __restrict__ wsv,
                           float* __restrict__ out) {
    __shared__ uint32_t px[C_ * SMH_ * PXW_];   // 3672 u32 = 14688 B

    const int blk = blockIdx.x;
    const int bx = blk % TILES_X_;
    const int by = (blk / TILES_X_) % TILES_Y_;
    const int b  = blk / (TILES_X_ * TILES_Y_);
    const int ox0 = bx * TX_;
    const int oy0 = by * TY_;

    const int tid  = threadIdx.x;
    const int lane = tid & 63;
    const int wv   = tid >> 6;
    const int nf   = lane & 15;
    const int g    = lane >> 4;

    const float* xb = x + (size_t)b * (C_ * H_ * W_);

    // ---- staging: 32 lanes/row, float2 + 1 scalar -> 2 pairs, ds_write_b64 ----
    {
        const int l5    = tid & 31;         // 0..31 -> pairs 2*l5, 2*l5+1
        const int rbase = tid >> 5;         // 0..7
        const int x0    = 2 * l5;
        #pragma unroll
        for (int pass = 0; pass < 7; ++pass) {
            int rg = pass * 8 + rbase;      // 0..55
            if (rg < C_ * SMH_) {
                int c  = rg / SMH_;
                int rr = rg - SMH_ * c;
                int gy = min(oy0 + rr, H_ - 1);
                const float* xrow = xb + (c * H_ + gy) * W_;
                float2 v01 = *(const float2*)(xrow + ox0 + x0);     // 8B-aligned
                float  v2  = xrow[min(ox0 + x0 + 2, W_ - 1)];
                uint2 pk = make_uint2(pack2bf(v01.x, v01.y), pack2bf(v01.y, v2));
                *reinterpret_cast<uint2*>(&px[(c * SMH_ + rr) * PXW_ + x0]) = pk;
            }
        }
        // extras: pairs x=64,65 per (c,r): 108 single-shot items
        if (tid < C_ * SMH_ * 2) {
            int c   = (tid >= 36) + (tid >= 72);
            int rem = tid - 36 * c;
            int r   = rem >> 1;
            int xx  = 64 + (rem & 1);
            int gy  = min(oy0 + r, H_ - 1);
            const float* xrow = xb + (c * H_ + gy) * W_;
            float v0 = xrow[min(ox0 + xx,     W_ - 1)];
            float v1 = xrow[min(ox0 + xx + 1, W_ - 1)];
            px[(c * SMH_ + r) * PXW_ + xx] = pack2bf(v0, v1);
        }
    }

    // ---- baked fragments (coalesced dwordx4; L2/L3-hot, 3 KB total) ----
    bf16x8 wf1 = __builtin_bit_cast(bf16x8, wsv[lane]);
    bf16x8 wf2 = __builtin_bit_cast(bf16x8, wsv[64 + lane]);
    f32x4  bi  = __builtin_bit_cast(f32x4,  wsv[128 + lane]);

    // ---- loop-invariant slot bases (u32 elems); RL = c*18+ky of slot row ----
    const int rl0 = (g == 1) ? 20 : (g == 2) ? 1  : (g == 3) ? 37 : 0;   // rows {0,5,1,7}
    const int rl1 = (g == 1) ? 18 : (g == 2) ? 19 : (g == 3) ? 36 : 2;   // rows {2,3,4,6}
    const int base0 = (rl0 + 4 * wv) * PXW_ + nf;
    const int base1 = (rl1 + 4 * wv) * PXW_ + nf;
    const int base2 = (38  + 4 * wv) * PXW_ + nf;   // R=8: c2ky2 (broadcast)
    const int baddr = (lane ^ 32) << 2;             // hoisted ds_bpermute address

    __syncthreads();

    // ---- per row: 4 MFMA sets -> in-lane min (scalars only, R7-proven
    //      pattern: flat array, static indices, explicit ternaries) ----
    const size_t orow0 = ((size_t)b * OH_ + (oy0 + 4 * wv)) * OW_ + ox0;

    #pragma unroll
    for (int row = 0; row < 4; ++row) {
        float mr[4];
        #pragma unroll
        for (int sx = 0; sx < 4; ++sx) {
            const int off = row * PXW_ + sx * 16;   // compile-time per set
            uint32_t r0 = px[base0 + off];
            uint32_t r1 = px[base0 + off + 2];
            uint32_t r2 = px[base1 + off];
            uint32_t r3 = px[base1 + off + 2];
            bf16x8 tf1 = __builtin_bit_cast(bf16x8, uint4{r0, r1, r2, r3});
            uint32_t s0 = px[base2 + off];
            uint32_t s1 = px[base2 + off + 2];
            bf16x8 tf2 = __builtin_bit_cast(bf16x8, uint4{s0, s1, 0u, 0u});

            f32x4 acc = __builtin_amdgcn_mfma_f32_16x16x32_bf16(wf1, tf1, bi, 0, 0, 0);
            acc = __builtin_amdgcn_mfma_f32_16x16x32_bf16(wf2, tf2, acc, 0, 0, 0);

            mr[sx] = fminf(fminf(acc[0], acc[1]), fminf(acc[2], acc[3]));
        }

        // batched xor16: 4 independent swizzles (latency overlaps)
        #pragma unroll
        for (int sx = 0; sx < 4; ++sx) {
            int sw = __builtin_amdgcn_ds_swizzle(
                __builtin_bit_cast(int, mr[sx]), 0x401F);
            mr[sx] = fminf(mr[sx], __builtin_bit_cast(float, sw));
        }

        // select-before-bpermute: own slice (sx=g) and partner slice (sx=g^2)
        float a = mr[0];
        a = (g == 1) ? mr[1] : a;
        a = (g == 2) ? mr[2] : a;
        a = (g == 3) ? mr[3] : a;
        float cc = mr[2];
        cc = (g == 1) ? mr[3] : cc;
        cc = (g == 2) ? mr[0] : cc;
        cc = (g == 3) ? mr[1] : cc;
        int bp = __builtin_amdgcn_ds_bpermute(baddr, __builtin_bit_cast(int, cc));
        float mm = fminf(a, __builtin_bit_cast(float, bp));
        float t = fast_tanh(fast_tanh(mm));

        int oy = oy0 + 4 * wv + row;
        int ox = ox0 + lane;
        if (oy < OH_ && ox < OW_)
            out[orow0 + (size_t)row * OW_ + lane] = t;
    }
}

extern "C" void kernel_launch(void* const* d_in, const int* in_sizes, int n_in,
                              void* d_out, int out_size, void* d_ws, size_t ws_size,
                              hipStream_t stream) {
    const float* x    = (const float*)d_in[0];
    const float* wgt  = (const float*)d_in[1];
    const float* bias = (const float*)d_in[2];
    float* out = (float*)d_out;

    conv_prep<<<1, 64, 0, stream>>>(wgt, bias, (uint16_t*)d_ws);
    conv3x3_min_tanh_mfma<<<dim3(B_ * TILES_X_ * TILES_Y_), 256, 0, stream>>>(
        x, (const uint4*)d_ws, out);
}

// Round 13
// 80.506 us; speedup vs baseline: 2.4656x; 1.0387x over previous
//
#include <hip/hip_runtime.h>
#include <hip/hip_bf16.h>
#include <stdint.h>

// Problem constants
#define B_  64
#define C_  3
#define H_  512
#define W_  512
#define OC_ 16
#define OH_ 510
#define OW_ 510

// Tile geometry: 256-thread block -> 64(x) x 16(y) outputs; wave wv owns rows
// 4wv..4wv+3; per wave 16 MFMA sets (4 rows x 4 sx), 2 MFMAs per set (K=36).
#define TX_ 64
#define TY_ 16
#define TILES_X_ 8    // ceil(510/64)
#define TILES_Y_ 32   // ceil(510/16)
#define SMH_ 18       // value rows per channel (TY+2)
#define PXW_ 68       // u32 pair slots per row (x=0..67; reads reach x=65)

typedef __attribute__((ext_vector_type(8))) short bf16x8;   // MFMA A/B frag
typedef __attribute__((ext_vector_type(4))) float f32x4;    // MFMA C/D frag

// NaN-safe tanh: 1 - 2/(e^{2x}+1); e=inf -> 1 (no inf/inf NaN).
__device__ __forceinline__ float fast_tanh(float v) {
    float e = __expf(2.0f * v);
    return 1.0f - 2.0f * __builtin_amdgcn_rcpf(e + 1.0f);
}
__device__ __forceinline__ uint16_t bf16u(float f) {
    __hip_bfloat16 h = __float2bfloat16(f);   // RNE
    return __builtin_bit_cast(uint16_t, h);
}
__device__ __forceinline__ uint32_t pack2bf(float v0, float v1) {
    return (uint32_t)bf16u(v0) | ((uint32_t)bf16u(v1) << 16);
}

// Row ids R = c*3+ky (0..8). Bank-balanced slot assignment (bank base mod 32
// of row R is 4*(c*18+ky) mod 32):
//   slot0 rows per g: {0:bank0, 5:16, 1:4, 7:20} -> 2 lanes/bank (free)
//   slot1 rows per g: {2:8, 3:8, 4:12, 6:16}     -> ~2.75-way
// B reg j: j0=slot0+xs0, j1=slot0+xs2, j2=slot1+xs0, j3=slot1+xs2; k=8g+2j+h.
// MFMA2: R=8 (c2ky2) at g==0 slots; B-side wave-broadcast (free).

// ---- prep kernel: bake permuted A-fragments + bias into ws (3 KB) ----
// ws layout: [0) wf1 u16[64][8]; [1024) wf2 u16[64][8]; [2048) bias f32[64][4]
__global__ void conv_prep(const float* __restrict__ wgt,
                          const float* __restrict__ bias,
                          uint16_t* __restrict__ ws16) {
    const int lane = threadIdx.x;        // 0..63
    const int oc = lane & 15, g = lane >> 4;
    const int R0 = (g == 1) ? 5 : (g == 2) ? 1 : (g == 3) ? 7 : 0;
    const int R1 = (g == 1) ? 3 : (g == 2) ? 4 : (g == 3) ? 6 : 2;
    #pragma unroll
    for (int e = 0; e < 8; ++e) {
        int j = e >> 1, h = e & 1;
        int R  = (j < 2) ? R0 : R1;
        int kx = ((j & 1) << 1) + h;          // xs + h
        float w = (kx < 3) ? wgt[oc * 27 + 3 * R + kx] : 0.0f;
        ws16[lane * 8 + e] = bf16u(w);
        float w2 = 0.0f;
        if (g == 0 && e < 4 && kx < 3) w2 = wgt[oc * 27 + 24 + kx];  // R=8
        ws16[512 + lane * 8 + e] = bf16u(w2);
    }
    float* bv = (float*)(ws16 + 1024);
    #pragma unroll
    for (int r = 0; r < 4; ++r) bv[lane * 4 + r] = bias[g * 4 + r];
}

__global__ __launch_bounds__(256)
void conv3x3_min_tanh_mfma(const float* __restrict__ x,
                           const uint4* __restrict__ wsv,
                           float* __restrict__ out) {
    __shared__ uint32_t px[C_ * SMH_ * PXW_];   // 3672 u32 = 14688 B

    const int blk = blockIdx.x;
    const int bx = blk % TILES_X_;
    const int by = (blk / TILES_X_) % TILES_Y_;
    const int b  = blk / (TILES_X_ * TILES_Y_);
    const int ox0 = bx * TX_;
    const int oy0 = by * TY_;

    const int tid  = threadIdx.x;
    const int lane = tid & 63;
    const int wv   = tid >> 6;
    const int nf   = lane & 15;
    const int g    = lane >> 4;

    const float* xb = x + (size_t)b * (C_ * H_ * W_);

    // ---- staging: float4 + 1 scalar -> 4 packed pairs -> ds_write_b128 ----
    // thread t: x0 = 4*(t&15) (0..60), row-group = t>>4; 4 passes x 16 lines
    // cover the 54 (c,row) lines (c-major, line id = rg).
    {
        const int x0   = 4 * (tid & 15);
        const int rgrp = tid >> 4;          // 0..15
        #pragma unroll
        for (int pass = 0; pass < 4; ++pass) {
            int rg = pass * 16 + rgrp;      // 0..63
            if (rg < C_ * SMH_) {
                int c  = (rg >= SMH_) + (rg >= 2 * SMH_);
                int rr = rg - SMH_ * c;
                int gy = min(oy0 + rr, H_ - 1);
                const float* xrow = xb + (c * H_ + gy) * W_;
                float4 v = *(const float4*)(xrow + ox0 + x0);       // 16B-aligned
                float  v4 = xrow[min(ox0 + x0 + 4, W_ - 1)];
                uint4 pk;
                pk.x = pack2bf(v.x, v.y);
                pk.y = pack2bf(v.y, v.z);
                pk.z = pack2bf(v.z, v.w);
                pk.w = pack2bf(v.w, v4);
                *reinterpret_cast<uint4*>(&px[rg * PXW_ + x0]) = pk;  // b128, aligned
            }
        }
        // extras: pairs x=64,65 per (c,r): 108 single-shot items
        if (tid < C_ * SMH_ * 2) {
            int c   = (tid >= 36) + (tid >= 72);
            int rem = tid - 36 * c;
            int r   = rem >> 1;
            int xx  = 64 + (rem & 1);
            int gy  = min(oy0 + r, H_ - 1);
            const float* xrow = xb + (c * H_ + gy) * W_;
            float v0 = xrow[min(ox0 + xx,     W_ - 1)];
            float v1 = xrow[min(ox0 + xx + 1, W_ - 1)];
            px[(c * SMH_ + r) * PXW_ + xx] = pack2bf(v0, v1);
        }
    }

    // ---- baked fragments (coalesced dwordx4; L2/L3-hot, 3 KB total) ----
    bf16x8 wf1 = __builtin_bit_cast(bf16x8, wsv[lane]);
    bf16x8 wf2 = __builtin_bit_cast(bf16x8, wsv[64 + lane]);
    f32x4  bi  = __builtin_bit_cast(f32x4,  wsv[128 + lane]);

    // ---- loop-invariant slot bases (u32 elems); RL = c*18+ky of slot row ----
    const int rl0 = (g == 1) ? 20 : (g == 2) ? 1  : (g == 3) ? 37 : 0;   // rows {0,5,1,7}
    const int rl1 = (g == 1) ? 18 : (g == 2) ? 19 : (g == 3) ? 36 : 2;   // rows {2,3,4,6}
    const int base0 = (rl0 + 4 * wv) * PXW_ + nf;
    const int base1 = (rl1 + 4 * wv) * PXW_ + nf;
    const int base2 = (38  + 4 * wv) * PXW_ + nf;   // R=8: c2ky2 (broadcast)
    const int baddr = (lane ^ 32) << 2;             // hoisted ds_bpermute address

    __syncthreads();

    // ---- per row: 4 MFMA sets -> in-lane min -> PROVEN epilogue
    //      (4x ds_swizzle xor16, select-before-bpermute xor32) ----
    const size_t orow0 = ((size_t)b * OH_ + (oy0 + 4 * wv)) * OW_ + ox0;

    #pragma unroll
    for (int row = 0; row < 4; ++row) {
        float mr[4];
        #pragma unroll
        for (int sx = 0; sx < 4; ++sx) {
            const int off = row * PXW_ + sx * 16;   // compile-time per set
            uint32_t r0 = px[base0 + off];
            uint32_t r1 = px[base0 + off + 2];
            uint32_t r2 = px[base1 + off];
            uint32_t r3 = px[base1 + off + 2];
            bf16x8 tf1 = __builtin_bit_cast(bf16x8, uint4{r0, r1, r2, r3});
            uint32_t s0 = px[base2 + off];
            uint32_t s1 = px[base2 + off + 2];
            bf16x8 tf2 = __builtin_bit_cast(bf16x8, uint4{s0, s1, 0u, 0u});

            f32x4 acc = __builtin_amdgcn_mfma_f32_16x16x32_bf16(wf1, tf1, bi, 0, 0, 0);
            acc = __builtin_amdgcn_mfma_f32_16x16x32_bf16(wf2, tf2, acc, 0, 0, 0);

            mr[sx] = fminf(fminf(acc[0], acc[1]), fminf(acc[2], acc[3]));
        }

        // batched xor16: 4 independent swizzles (latency overlaps)
        #pragma unroll
        for (int sx = 0; sx < 4; ++sx) {
            int sw = __builtin_amdgcn_ds_swizzle(
                __builtin_bit_cast(int, mr[sx]), 0x401F);
            mr[sx] = fminf(mr[sx], __builtin_bit_cast(float, sw));
        }

        // select-before-bpermute: own slice (sx=g) and partner slice (sx=g^2)
        float a = mr[0];
        a = (g == 1) ? mr[1] : a;
        a = (g == 2) ? mr[2] : a;
        a = (g == 3) ? mr[3] : a;
        float cc = mr[2];
        cc = (g == 1) ? mr[3] : cc;
        cc = (g == 2) ? mr[0] : cc;
        cc = (g == 3) ? mr[1] : cc;
        int bp = __builtin_amdgcn_ds_bpermute(baddr, __builtin_bit_cast(int, cc));
        float mm = fminf(a, __builtin_bit_cast(float, bp));
        float t = fast_tanh(fast_tanh(mm));

        int oy = oy0 + 4 * wv + row;
        int ox = ox0 + lane;
        if (oy < OH_ && ox < OW_)
            out[orow0 + (size_t)row * OW_ + lane] = t;
    }
}

extern "C" void kernel_launch(void* const* d_in, const int* in_sizes, int n_in,
                              void* d_out, int out_size, void* d_ws, size_t ws_size,
                              hipStream_t stream) {
    const float* x    = (const float*)d_in[0];
    const float* wgt  = (const float*)d_in[1];
    const float* bias = (const float*)d_in[2];
    float* out = (float*)d_out;

    conv_prep<<<1, 64, 0, stream>>>(wgt, bias, (uint16_t*)d_ws);
    conv3x3_min_tanh_mfma<<<dim3(B_ * TILES_X_ * TILES_Y_), 256, 0, stream>>>(
        x, (const uint4*)d_ws, out);
}